// Round 3
// baseline (2103.445 us; speedup 1.0000x reference)
//
#include <hip/hip_runtime.h>

#define TT   64
#define NB   8
#define NN   512
#define HID  128
#define G4   512
#define EE   8192
#define SBLK 16
#define NTHR 512

// ---- bf16 helpers (RNE) ----
__device__ __forceinline__ unsigned short f2bf(float f){
  unsigned u = __float_as_uint(f);
  return (unsigned short)((u + 0x7FFFu + ((u >> 16) & 1u)) >> 16);
}
__device__ __forceinline__ float bf2f(unsigned short b){
  return __uint_as_float(((unsigned)b) << 16);
}

__device__ __forceinline__ float sigf(float x){ return 1.0f/(1.0f+expf(-x)); }

using short8 = __attribute__((ext_vector_type(8))) short;
using f32x4  = __attribute__((ext_vector_type(4))) float;

// async global->LDS, 16B per lane; LDS dest = wave-uniform base + lane*16
__device__ __forceinline__ void gload16(const float* g, float* l){
  __builtin_amdgcn_global_load_lds(
      (const __attribute__((address_space(1))) void*)g,
      (__attribute__((address_space(3))) void*)l, 16, 0, 0);
}

// ---------------------------------------------------------------------------
// Weight prep: f32 [512][128] x5 -> bf16 hi/lo planes in MFMA B-fragment order.
// Chunk c = mat*8 + kt*2 + half (40 chunks x 16384 bf16 = 32KB each):
//   [hi: nl(16) x lane(64) x 8 bf16][lo: same]
// lane l elem j <-> W[n = (half*16+nl)*16 + (l&15)][k = kt*32 + 8*(l>>4) + j]
// ---------------------------------------------------------------------------
__global__ void prep_w(const float* __restrict__ whh0, const float* __restrict__ wih1,
                       const float* __restrict__ whh1, const float* __restrict__ wih2,
                       const float* __restrict__ whh2, unsigned short* __restrict__ wp)
{
  int idx = blockIdx.x*256 + threadIdx.x;      // 5*512*128 total
  int mat = idx >> 16;
  int r   = (idx >> 7) & 511;
  int k   = idx & 127;
  const float* src = (mat==0)?whh0:(mat==1)?wih1:(mat==2)?whh1:(mat==3)?wih2:whh2;
  float v = src[r*HID + k];
  unsigned short hi = f2bf(v);
  unsigned short lo = f2bf(v - bf2f(hi));
  int kt = k >> 5, kk = k & 31, s0 = kk >> 3, j = kk & 7;
  int nt = r >> 4, half = nt >> 4, nl = nt & 15;
  int l  = (r & 15) + 16*s0;
  int off = (mat*8 + kt*2 + half)*16384 + nl*512 + l*8 + j;
  wp[off]        = hi;
  wp[off + 8192] = lo;
}

// ---------------------------------------------------------------------------
// Fused 3-layer LSTM scan, MFMA split-bf16, T3+T4 pipelined version.
// 3 x 32KB chunk buffers, prefetch depth 2, counted vmcnt(4) + raw s_barrier
// (never vmcnt(0) in the main loop). x preloaded to LDS so the loop contains
// no compiler-tracked VMEM loads (keeps compiler from emitting vmcnt(0)).
// ---------------------------------------------------------------------------
__global__ __launch_bounds__(NTHR) void lstm_scan(
    const float* __restrict__ x,    const float* __restrict__ wih0,
    const float* __restrict__ bih0, const float* __restrict__ bhh0,
    const float* __restrict__ bih1, const float* __restrict__ bhh1,
    const float* __restrict__ bih2, const float* __restrict__ bhh2,
    const unsigned short* __restrict__ wp, float* __restrict__ feats)
{
  __shared__ __align__(16) float Wb[3*8192];            // 96 KB, 3 x 32KB chunks
  __shared__ __align__(16) unsigned short hb[3*2*2048]; // 24 KB: 3 layers x {hi,lo} x [16][128]
  __shared__ __align__(16) float xall[TT*SBLK];         // 4 KB: all x for this block

  const int tid  = threadIdx.x;
  const int lane = tid & 63, wv = tid >> 6;
  const int row  = lane & 15;                 // seq-row of A frag / N-col of D
  const int u    = 16*wv + row;               // unit owned by this lane
  const int s0   = blockIdx.x * SBLK;
  const int b    = s0 >> 9, n0 = s0 & (NN-1);
  const float* wpf = (const float*)wp;

  for (int i = tid; i < 3*2*2048; i += NTHR) hb[i] = 0;
  for (int i = tid; i < TT*SBLK; i += NTHR)
    xall[i] = x[(b*TT + (i>>4))*NN + n0 + (i&15)];

  // biases (both b_ih+b_hh) and wih0 column, per-gate, in registers
  float bL0[4], bL1[4], bL2[4], w0g[4];
  #pragma unroll
  for (int g=0; g<4; g++){
    bL0[g] = bih0[g*HID+u] + bhh0[g*HID+u];
    bL1[g] = bih1[g*HID+u] + bhh1[g*HID+u];
    bL2[g] = bih2[g*HID+u] + bhh2[g*HID+u];
    w0g[g] = wih0[g*HID+u];
  }

  // h-plane write offsets (bytes within a 4KB plane), one per owned seq
  int wbyte[4];
  #pragma unroll
  for (int r=0; r<4; r++){
    int sq = 4*(lane>>4) + r;
    wbyte[r] = sq*256 + ((u*2) ^ ((sq&7)<<4));
  }
  // B-fragment byte offsets within a chunk buffer
  const int bA = wv*1024 + lane*16;           // nl = wv
  const int bB = (wv+8)*1024 + lane*16;       // nl = wv+8

  f32x4 acc[4];
  float cs0[4]={0,0,0,0}, cs1[4]={0,0,0,0}, cs2[4]={0,0,0,0};
  float hlast[4]={0,0,0,0};

  // prologue: DMA chunk 0 -> buf 0, chunk 1 -> buf 1 (8 loads/thread in flight)
  #pragma unroll
  for (int i=0;i<4;i++) gload16(wpf + i*2048 + tid*4, &Wb[i*2048 + tid*4]);
  #pragma unroll
  for (int i=0;i<4;i++) gload16(wpf + 8192 + i*2048 + tid*4, &Wb[8192 + i*2048 + tid*4]);

  int pfc = 2, pfb = 2, curb = 0;   // prefetch chunk idx / buf idx, current buf

  #pragma unroll 1
  for (int t=0;t<TT;t++){
    #pragma unroll 1
    for (int c=0;c<40;c++){
      // --- T4: counted wait. Chunk c (mine) landed; chunk c+1 stays in flight.
      asm volatile("s_waitcnt vmcnt(4) lgkmcnt(0)" ::: "memory");
      __builtin_amdgcn_s_barrier();          // all waves' chunk-c data in LDS
      __builtin_amdgcn_sched_barrier(0);

      // --- prefetch chunk c+2 into the buffer freed by chunk c-1
      {
        const float* src = wpf + pfc*8192;
        float* dst = &Wb[pfb*8192];
        #pragma unroll
        for (int i=0;i<4;i++) gload16(src + i*2048 + tid*4, dst + i*2048 + tid*4);
        pfc = (pfc+1 == 40) ? 0 : pfc+1;
        pfb = (pfb+1 == 3)  ? 0 : pfb+1;
      }
      __builtin_amdgcn_sched_barrier(0);     // keep DMA issue ahead of ds_reads

      if (c==0){
        #pragma unroll
        for (int g=0;g<4;g++) acc[g] = (f32x4){bL0[g],bL0[g],bL0[g],bL0[g]};
      } else if (c==8){
        #pragma unroll
        for (int g=0;g<4;g++) acc[g] = (f32x4){bL1[g],bL1[g],bL1[g],bL1[g]};
      } else if (c==24){
        #pragma unroll
        for (int g=0;g<4;g++) acc[g] = (f32x4){bL2[g],bL2[g],bL2[g],bL2[g]};
      }

      // A source plane: c<16 -> h0, c<32 -> h1, else h2 ; kt within matrix
      const int pl = (c<16)?0:((c<32)?1:2);
      const int kt = (c>>1)&3;
      const int rbyte = row*256 + (((kt<<6) + ((lane>>4)<<4)) ^ ((row&7)<<4));
      const char* hbase = (const char*)hb + pl*8192;
      short8 ahh = *(const short8*)(hbase + rbyte);
      short8 ahl = *(const short8*)(hbase + 4096 + rbyte);
      const char* wbase = (const char*)Wb + curb*32768;
      short8 bh0 = *(const short8*)(wbase + bA);
      short8 bl0 = *(const short8*)(wbase + 16384 + bA);
      short8 bh1 = *(const short8*)(wbase + bB);
      short8 bl1 = *(const short8*)(wbase + 16384 + bB);
      curb = (curb+1 == 3) ? 0 : curb+1;

      if ((c&1)==0){  // N-tiles 0..15 -> gates i,f
        acc[0] = __builtin_amdgcn_mfma_f32_16x16x32_bf16(ahh, bh0, acc[0],0,0,0);
        acc[0] = __builtin_amdgcn_mfma_f32_16x16x32_bf16(ahl, bh0, acc[0],0,0,0);
        acc[0] = __builtin_amdgcn_mfma_f32_16x16x32_bf16(ahh, bl0, acc[0],0,0,0);
        acc[1] = __builtin_amdgcn_mfma_f32_16x16x32_bf16(ahh, bh1, acc[1],0,0,0);
        acc[1] = __builtin_amdgcn_mfma_f32_16x16x32_bf16(ahl, bh1, acc[1],0,0,0);
        acc[1] = __builtin_amdgcn_mfma_f32_16x16x32_bf16(ahh, bl1, acc[1],0,0,0);
      } else {        // N-tiles 16..31 -> gates g,o
        acc[2] = __builtin_amdgcn_mfma_f32_16x16x32_bf16(ahh, bh0, acc[2],0,0,0);
        acc[2] = __builtin_amdgcn_mfma_f32_16x16x32_bf16(ahl, bh0, acc[2],0,0,0);
        acc[2] = __builtin_amdgcn_mfma_f32_16x16x32_bf16(ahh, bl0, acc[2],0,0,0);
        acc[3] = __builtin_amdgcn_mfma_f32_16x16x32_bf16(ahh, bh1, acc[3],0,0,0);
        acc[3] = __builtin_amdgcn_mfma_f32_16x16x32_bf16(ahl, bh1, acc[3],0,0,0);
        acc[3] = __builtin_amdgcn_mfma_f32_16x16x32_bf16(ahh, bl1, acc[3],0,0,0);
      }

      // CELL: raw barrier (lgkm-drained, NOT vmcnt-drained) so the in-flight
      // weight DMAs stay outstanding across the gate nonlinearity.
      #define CELL(Lc, CST, XTERM, LAST)                                        \
        { asm volatile("s_waitcnt lgkmcnt(0)" ::: "memory");                    \
          __builtin_amdgcn_s_barrier();                                         \
          __builtin_amdgcn_sched_barrier(0);                                    \
          _Pragma("unroll")                                                     \
          for (int r=0;r<4;r++){                                                \
            float iv=acc[0][r], fv=acc[1][r], gv=acc[2][r], ov=acc[3][r];       \
            if (XTERM){ float xv=xall[t*SBLK + 4*(lane>>4)+r];                  \
                        iv+=xv*w0g[0]; fv+=xv*w0g[1];                           \
                        gv+=xv*w0g[2]; ov+=xv*w0g[3]; }                         \
            float cn = sigf(fv)*CST[r] + sigf(iv)*tanhf(gv);                    \
            CST[r]=cn; float hn = sigf(ov)*tanhf(cn);                           \
            unsigned short hh = f2bf(hn);                                       \
            unsigned short hl = f2bf(hn - bf2f(hh));                            \
            *(unsigned short*)((char*)hb + (Lc)*8192        + wbyte[r]) = hh;   \
            *(unsigned short*)((char*)hb + (Lc)*8192 + 4096 + wbyte[r]) = hl;   \
            if (LAST) hlast[r]=hn; } }

      if      (c==7 ) CELL(0, cs0, 1, 0)
      else if (c==23) CELL(1, cs1, 0, 0)
      else if (c==39) CELL(2, cs2, 0, 1)
      #undef CELL
    }
  }
  #pragma unroll
  for (int r=0;r<4;r++)
    feats[(s0 + 4*(lane>>4) + r)*HID + u] = hlast[r];
}

// ---------------------------------------------------------------------------
// GCN part (unchanged from verified baseline)
// ---------------------------------------------------------------------------
template<int KOUT>
__global__ void gcn_gemm(const float* __restrict__ in, const float* __restrict__ W,
                         const float* __restrict__ pre_bias, float* __restrict__ out)
{
  int id  = blockIdx.x*256 + threadIdx.x;
  int row = id / KOUT;
  int o   = id & (KOUT-1);
  const float4* a4 = (const float4*)(in + row*HID);
  const float4* w4 = (const float4*)(W + o*HID);
  float acc = 0.f;
  if (pre_bias){
    const float4* b4 = (const float4*)pre_bias;
    #pragma unroll 8
    for (int k=0;k<HID/4;k++){
      float4 av=a4[k], wv=w4[k], bv=b4[k];
      acc += fmaxf(av.x+bv.x,0.f)*wv.x + fmaxf(av.y+bv.y,0.f)*wv.y
           + fmaxf(av.z+bv.z,0.f)*wv.z + fmaxf(av.w+bv.w,0.f)*wv.w;
    }
  } else {
    #pragma unroll 8
    for (int k=0;k<HID/4;k++){
      float4 av=a4[k], wv=w4[k];
      acc += av.x*wv.x + av.y*wv.y + av.z*wv.z + av.w*wv.w;
    }
  }
  out[id] = acc;
}

__global__ void deg_init(float* deg){
  int i = blockIdx.x*256 + threadIdx.x;
  if (i < NN) deg[i] = 1.0f;             // self-loop
}
__global__ void deg_edges(const int* __restrict__ ei, float* deg){
  int e = blockIdx.x*256 + threadIdx.x;
  if (e < EE) atomicAdd(&deg[ei[EE+e]], 1.0f);
}
__global__ void build_A(const int* __restrict__ ei, const float* __restrict__ deg,
                        float* __restrict__ A){
  int e = blockIdx.x*256 + threadIdx.x;
  if (e < EE){
    int s = ei[e], d = ei[EE+e];
    atomicAdd(&A[d*NN+s], rsqrtf(deg[s])*rsqrtf(deg[d]));
  } else if (e < EE+NN){
    int n = e - EE;
    atomicAdd(&A[n*NN+n], 1.0f/deg[n]);
  }
}

template<int KOUT>
__global__ __launch_bounds__(512) void gcn_agg(const float* __restrict__ A,
    const float* __restrict__ X, float* __restrict__ Y)
{
  const int F4 = KOUT/4;
  const int TN = 16;
  __shared__ __align__(16) float As[TN*NN];
  const int b = blockIdx.x, n0 = blockIdx.y*TN;
  const int tid = threadIdx.x;
  const int f4 = tid & (F4-1), nr = tid / F4;
  for (int i = tid; i < TN*NN; i += TN*F4) As[i] = A[n0*NN + i];
  __syncthreads();
  const float* Xb = X + b*NN*KOUT + f4*4;
  const float* Ar = As + nr*NN;
  float4 s = {0,0,0,0};
  #pragma unroll 4
  for (int m=0;m<NN;m++){
    float a = Ar[m];
    float4 xv = *(const float4*)(Xb + m*KOUT);
    s.x += a*xv.x; s.y += a*xv.y; s.z += a*xv.z; s.w += a*xv.w;
  }
  *(float4*)(Y + (b*NN + n0 + nr)*KOUT + f4*4) = s;
}

__global__ void finalize(const float* __restrict__ agg2, const float* __restrict__ b2,
                         const float* __restrict__ clw, const float* __restrict__ clb,
                         float* __restrict__ out)
{
  __shared__ float red[256];
  int bb = blockIdx.x, tid = threadIdx.x;
  float acc = 0.f;
  for (int i = tid; i < NN*64; i += 256){
    int j = i & 63;
    float v = agg2[bb*NN*64 + i] + b2[j];
    acc += fmaxf(v, 0.f) * clw[j];
  }
  red[tid] = acc; __syncthreads();
  for (int sfd=128; sfd>0; sfd>>=1){
    if (tid < sfd) red[tid] += red[tid+sfd];
    __syncthreads();
  }
  if (tid==0) out[bb] = red[0]*(1.0f/NN) + clb[0];
}

extern "C" void kernel_launch(void* const* d_in, const int* in_sizes, int n_in,
                              void* d_out, int out_size, void* d_ws, size_t ws_size,
                              hipStream_t stream)
{
  const float* x    = (const float*)d_in[0];
  const int*   ei   = (const int*)  d_in[1];
  const float* wih0 = (const float*)d_in[2];
  const float* whh0 = (const float*)d_in[3];
  const float* bih0 = (const float*)d_in[4];
  const float* bhh0 = (const float*)d_in[5];
  const float* wih1 = (const float*)d_in[6];
  const float* whh1 = (const float*)d_in[7];
  const float* bih1 = (const float*)d_in[8];
  const float* bhh1 = (const float*)d_in[9];
  const float* wih2 = (const float*)d_in[10];
  const float* whh2 = (const float*)d_in[11];
  const float* bih2 = (const float*)d_in[12];
  const float* bhh2 = (const float*)d_in[13];
  const float* g1w  = (const float*)d_in[14];
  const float* g1b  = (const float*)d_in[15];
  const float* g2w  = (const float*)d_in[16];
  const float* g2b  = (const float*)d_in[17];
  const float* clw  = (const float*)d_in[18];
  const float* clb  = (const float*)d_in[19];
  float* out = (float*)d_out;

  char* ws = (char*)d_ws;
  float* feats = (float*)(ws);                 // [4096,128]  2 MB
  float* xl1   = (float*)(ws + 2097152);       // [8,512,128] 2 MB
  float* agg1  = (float*)(ws + 4194304);       // [8,512,128] 2 MB
  float* xl2   = (float*)(ws + 6291456);       // [8,512,64]  1 MB
  float* agg2  = (float*)(ws + 7340032);       // [8,512,64]  1 MB
  float* A     = (float*)(ws + 8388608);       // [512,512]   1 MB
  float* deg   = (float*)(ws + 9437184);       // [512]
  // bf16 hi/lo weight planes: 40 chunks x 32KB = 1.31 MB.
  // Overlaps xl2/agg2 region: wp is consumed by lstm_scan BEFORE xl2/agg2
  // are ever written (strict stream order), so reuse is safe.
  unsigned short* wpW = (unsigned short*)(ws + 6291456);

  prep_w<<<(5*G4*HID)/256, 256, 0, stream>>>(whh0, wih1, whh1, wih2, whh2, wpW);

  hipMemsetAsync(A, 0, NN*NN*sizeof(float), stream);
  deg_init <<<2, 256, 0, stream>>>(deg);
  deg_edges<<<EE/256, 256, 0, stream>>>(ei, deg);
  build_A  <<<(EE+NN+255)/256, 256, 0, stream>>>(ei, deg, A);

  lstm_scan<<<256, NTHR, 0, stream>>>(x, wih0, bih0, bhh0,
      bih1, bhh1, bih2, bhh2, wpW, feats);

  gcn_gemm<128><<<(4096*128)/256, 256, 0, stream>>>(feats, g1w, nullptr, xl1);
  gcn_agg<128><<<dim3(NB, NN/16), 512, 0, stream>>>(A, xl1, agg1);
  gcn_gemm<64><<<(4096*64)/256, 256, 0, stream>>>(agg1, g2w, g1b, xl2);
  gcn_agg<64><<<dim3(NB, NN/16), 256, 0, stream>>>(A, xl2, agg2);
  finalize<<<NB, 256, 0, stream>>>(agg2, g2b, clw, clb, out);
}

// Round 5
// 1744.706 us; speedup vs baseline: 1.2056x; 1.2056x over previous
//
#include <hip/hip_runtime.h>

#define TT   64
#define NB   8
#define NN   512
#define HID  128
#define G4   512
#define EE   8192
#define SBLK 16
#define NTHR 512

__device__ __forceinline__ float sigf(float x){ return 1.0f/(1.0f+expf(-x)); }

using half8 = __attribute__((ext_vector_type(8))) _Float16;
using f32x4 = __attribute__((ext_vector_type(4))) float;

// async global->LDS, 16B per lane; LDS dest = wave-uniform base + lane*16
__device__ __forceinline__ void gload16(const float* g, float* l){
  __builtin_amdgcn_global_load_lds(
      (const __attribute__((address_space(1))) void*)g,
      (__attribute__((address_space(3))) void*)l, 16, 0, 0);
}

// ---------------------------------------------------------------------------
// Weight prep: f32 [512][128] x5 -> SINGLE fp16 plane in MFMA B-fragment order.
// Chunk c = mat*8 + kt*2 + half (40 chunks x 8192 fp16 = 16KB each):
//   [nl(16) x lane(64) x 8 fp16]
// lane l elem j <-> W[n = (half*16+nl)*16 + (l&15)][k = kt*32 + 8*(l>>4) + j]
// ---------------------------------------------------------------------------
__global__ void prep_w(const float* __restrict__ whh0, const float* __restrict__ wih1,
                       const float* __restrict__ whh1, const float* __restrict__ wih2,
                       const float* __restrict__ whh2, _Float16* __restrict__ wp)
{
  int idx = blockIdx.x*256 + threadIdx.x;      // 5*512*128 total
  int mat = idx >> 16;
  int r   = (idx >> 7) & 511;
  int k   = idx & 127;
  const float* src = (mat==0)?whh0:(mat==1)?wih1:(mat==2)?whh1:(mat==3)?wih2:whh2;
  float v = src[r*HID + k];
  int kt = k >> 5, kk = k & 31, s0 = kk >> 3, j = kk & 7;
  int nt = r >> 4, half = nt >> 4, nl = nt & 15;
  int l  = (r & 15) + 16*s0;
  wp[(mat*8 + kt*2 + half)*8192 + nl*512 + l*8 + j] = (_Float16)v;
}

// ---------------------------------------------------------------------------
// Fused 3-layer LSTM scan, MFMA fp16 (W single fp16, h split hi+lo fp16).
// 4 x 16KB chunk buffers, prefetch depth 3, counted vmcnt(4) + raw s_barrier
// (never vmcnt(0) in the main loop). x preloaded to LDS so the loop contains
// no compiler-tracked VMEM loads. Skeleton identical to the verified R3.
// ---------------------------------------------------------------------------
__global__ __launch_bounds__(NTHR) void lstm_scan(
    const float* __restrict__ x,    const float* __restrict__ wih0,
    const float* __restrict__ bih0, const float* __restrict__ bhh0,
    const float* __restrict__ bih1, const float* __restrict__ bhh1,
    const float* __restrict__ bih2, const float* __restrict__ bhh2,
    const _Float16* __restrict__ wp, float* __restrict__ feats)
{
  __shared__ __align__(16) float Wb[4*4096];       // 64 KB, 4 x 16KB chunks
  __shared__ __align__(16) _Float16 hb[3*2*2048];  // 24 KB: 3 layers x {hi,lo} x [16][128]
  __shared__ __align__(16) float xall[TT*SBLK];    // 4 KB: all x for this block

  const int tid  = threadIdx.x;
  const int lane = tid & 63, wv = tid >> 6;
  const int row  = lane & 15;                 // seq-row of A frag / N-col of D
  const int u    = 16*wv + row;               // unit owned by this lane
  const int s0   = blockIdx.x * SBLK;
  const int b    = s0 >> 9, n0 = s0 & (NN-1);
  const float* wpf = (const float*)wp;

  for (int i = tid; i < 3*2*2048; i += NTHR) hb[i] = (_Float16)0.0f;
  for (int i = tid; i < TT*SBLK; i += NTHR)
    xall[i] = x[(b*TT + (i>>4))*NN + n0 + (i&15)];

  // biases (both b_ih+b_hh) and wih0 column, per-gate, in registers
  float bL0[4], bL1[4], bL2[4], w0g[4];
  #pragma unroll
  for (int g=0; g<4; g++){
    bL0[g] = bih0[g*HID+u] + bhh0[g*HID+u];
    bL1[g] = bih1[g*HID+u] + bhh1[g*HID+u];
    bL2[g] = bih2[g*HID+u] + bhh2[g*HID+u];
    w0g[g] = wih0[g*HID+u];
  }

  // h-plane write offsets (bytes within a 4KB plane), one per owned seq
  int wbyte[4];
  #pragma unroll
  for (int r=0; r<4; r++){
    int sq = 4*(lane>>4) + r;
    wbyte[r] = sq*256 + ((u*2) ^ ((sq&7)<<4));
  }
  // B-fragment byte offsets within a 16KB chunk buffer
  const int bA = wv*1024 + lane*16;           // nl = wv
  const int bB = (wv+8)*1024 + lane*16;       // nl = wv+8

  f32x4 acc[4];
  float cs0[4]={0,0,0,0}, cs1[4]={0,0,0,0}, cs2[4]={0,0,0,0};
  float hlast[4]={0,0,0,0};

  // prologue: DMA chunks 0,1,2 -> bufs 0,1,2 (6 loads/thread in flight)
  #pragma unroll
  for (int q=0;q<3;q++){
    #pragma unroll
    for (int i=0;i<2;i++)
      gload16(wpf + q*2048*2 + i*2048 + tid*4, &Wb[q*4096 + i*2048 + tid*4]);
  }

  int pfc = 3, pfb = 3, curb = 0;   // prefetch chunk idx / buf idx, current buf

  #pragma unroll 1
  for (int t=0;t<TT;t++){
    #pragma unroll 1
    for (int c=0;c<40;c++){
      // --- counted wait: chunk c landed; chunks c+1,c+2 (4 loads) in flight.
      asm volatile("s_waitcnt vmcnt(4) lgkmcnt(0)" ::: "memory");
      __builtin_amdgcn_s_barrier();          // all waves' chunk-c data in LDS
      __builtin_amdgcn_sched_barrier(0);

      // --- prefetch chunk c+3 into the buffer freed by chunk c-1
      {
        const float* src = wpf + pfc*4096;
        float* dst = &Wb[pfb*4096];
        #pragma unroll
        for (int i=0;i<2;i++) gload16(src + i*2048 + tid*4, dst + i*2048 + tid*4);
        pfc = (pfc+1 == 40) ? 0 : pfc+1;
        pfb = (pfb+1) & 3;
      }
      __builtin_amdgcn_sched_barrier(0);     // keep DMA issue ahead of ds_reads

      if (c==0){
        #pragma unroll
        for (int g=0;g<4;g++) acc[g] = (f32x4){bL0[g],bL0[g],bL0[g],bL0[g]};
      } else if (c==8){
        #pragma unroll
        for (int g=0;g<4;g++) acc[g] = (f32x4){bL1[g],bL1[g],bL1[g],bL1[g]};
      } else if (c==24){
        #pragma unroll
        for (int g=0;g<4;g++) acc[g] = (f32x4){bL2[g],bL2[g],bL2[g],bL2[g]};
      }

      // A source plane: c<16 -> h0, c<32 -> h1, else h2 ; kt within matrix
      const int pl = (c<16)?0:((c<32)?1:2);
      const int kt = (c>>1)&3;
      const int rbyte = row*256 + (((kt<<6) + ((lane>>4)<<4)) ^ ((row&7)<<4));
      const char* hbase = (const char*)hb + pl*8192;
      half8 ahh = *(const half8*)(hbase + rbyte);
      half8 ahl = *(const half8*)(hbase + 4096 + rbyte);
      const char* wbase = (const char*)Wb + curb*16384;
      half8 bh0 = *(const half8*)(wbase + bA);
      half8 bh1 = *(const half8*)(wbase + bB);
      curb = (curb+1) & 3;

      if ((c&1)==0){  // N-tiles 0..15 -> gates i,f
        acc[0] = __builtin_amdgcn_mfma_f32_16x16x32_f16(ahh, bh0, acc[0],0,0,0);
        acc[0] = __builtin_amdgcn_mfma_f32_16x16x32_f16(ahl, bh0, acc[0],0,0,0);
        acc[1] = __builtin_amdgcn_mfma_f32_16x16x32_f16(ahh, bh1, acc[1],0,0,0);
        acc[1] = __builtin_amdgcn_mfma_f32_16x16x32_f16(ahl, bh1, acc[1],0,0,0);
      } else {        // N-tiles 16..31 -> gates g,o
        acc[2] = __builtin_amdgcn_mfma_f32_16x16x32_f16(ahh, bh0, acc[2],0,0,0);
        acc[2] = __builtin_amdgcn_mfma_f32_16x16x32_f16(ahl, bh0, acc[2],0,0,0);
        acc[3] = __builtin_amdgcn_mfma_f32_16x16x32_f16(ahh, bh1, acc[3],0,0,0);
        acc[3] = __builtin_amdgcn_mfma_f32_16x16x32_f16(ahl, bh1, acc[3],0,0,0);
      }

      // CELL: raw barrier (lgkm-drained, NOT vmcnt-drained) so the in-flight
      // weight DMAs stay outstanding across the gate nonlinearity.
      #define CELL(Lc, CST, XTERM, LAST)                                        \
        { asm volatile("s_waitcnt lgkmcnt(0)" ::: "memory");                    \
          __builtin_amdgcn_s_barrier();                                         \
          __builtin_amdgcn_sched_barrier(0);                                    \
          _Pragma("unroll")                                                     \
          for (int r=0;r<4;r++){                                                \
            float iv=acc[0][r], fv=acc[1][r], gv=acc[2][r], ov=acc[3][r];       \
            if (XTERM){ float xv=xall[t*SBLK + 4*(lane>>4)+r];                  \
                        iv+=xv*w0g[0]; fv+=xv*w0g[1];                           \
                        gv+=xv*w0g[2]; ov+=xv*w0g[3]; }                         \
            float cn = sigf(fv)*CST[r] + sigf(iv)*tanhf(gv);                    \
            CST[r]=cn; float hn = sigf(ov)*tanhf(cn);                           \
            _Float16 hh = (_Float16)hn;                                         \
            _Float16 hl = (_Float16)(hn - (float)hh);                           \
            *(_Float16*)((char*)hb + (Lc)*8192        + wbyte[r]) = hh;         \
            *(_Float16*)((char*)hb + (Lc)*8192 + 4096 + wbyte[r]) = hl;         \
            if (LAST) hlast[r]=hn; } }

      if      (c==7 ) CELL(0, cs0, 1, 0)
      else if (c==23) CELL(1, cs1, 0, 0)
      else if (c==39) CELL(2, cs2, 0, 1)
      #undef CELL
    }
  }
  #pragma unroll
  for (int r=0;r<4;r++)
    feats[(s0 + 4*(lane>>4) + r)*HID + u] = hlast[r];
}

// ---------------------------------------------------------------------------
// GCN part (unchanged from verified baseline)
// ---------------------------------------------------------------------------
template<int KOUT>
__global__ void gcn_gemm(const float* __restrict__ in, const float* __restrict__ W,
                         const float* __restrict__ pre_bias, float* __restrict__ out)
{
  int id  = blockIdx.x*256 + threadIdx.x;
  int row = id / KOUT;
  int o   = id & (KOUT-1);
  const float4* a4 = (const float4*)(in + row*HID);
  const float4* w4 = (const float4*)(W + o*HID);
  float acc = 0.f;
  if (pre_bias){
    const float4* b4 = (const float4*)pre_bias;
    #pragma unroll 8
    for (int k=0;k<HID/4;k++){
      float4 av=a4[k], wv=w4[k], bv=b4[k];
      acc += fmaxf(av.x+bv.x,0.f)*wv.x + fmaxf(av.y+bv.y,0.f)*wv.y
           + fmaxf(av.z+bv.z,0.f)*wv.z + fmaxf(av.w+bv.w,0.f)*wv.w;
    }
  } else {
    #pragma unroll 8
    for (int k=0;k<HID/4;k++){
      float4 av=a4[k], wv=w4[k];
      acc += av.x*wv.x + av.y*wv.y + av.z*wv.z + av.w*wv.w;
    }
  }
  out[id] = acc;
}

__global__ void deg_init(float* deg){
  int i = blockIdx.x*256 + threadIdx.x;
  if (i < NN) deg[i] = 1.0f;             // self-loop
}
__global__ void deg_edges(const int* __restrict__ ei, float* deg){
  int e = blockIdx.x*256 + threadIdx.x;
  if (e < EE) atomicAdd(&deg[ei[EE+e]], 1.0f);
}
__global__ void build_A(const int* __restrict__ ei, const float* __restrict__ deg,
                        float* __restrict__ A){
  int e = blockIdx.x*256 + threadIdx.x;
  if (e < EE){
    int s = ei[e], d = ei[EE+e];
    atomicAdd(&A[d*NN+s], rsqrtf(deg[s])*rsqrtf(deg[d]));
  } else if (e < EE+NN){
    int n = e - EE;
    atomicAdd(&A[n*NN+n], 1.0f/deg[n]);
  }
}

template<int KOUT>
__global__ __launch_bounds__(512) void gcn_agg(const float* __restrict__ A,
    const float* __restrict__ X, float* __restrict__ Y)
{
  const int F4 = KOUT/4;
  const int TN = 16;
  __shared__ __align__(16) float As[TN*NN];
  const int b = blockIdx.x, n0 = blockIdx.y*TN;
  const int tid = threadIdx.x;
  const int f4 = tid & (F4-1), nr = tid / F4;
  for (int i = tid; i < TN*NN; i += TN*F4) As[i] = A[n0*NN + i];
  __syncthreads();
  const float* Xb = X + b*NN*KOUT + f4*4;
  const float* Ar = As + nr*NN;
  float4 s = {0,0,0,0};
  #pragma unroll 4
  for (int m=0;m<NN;m++){
    float a = Ar[m];
    float4 xv = *(const float4*)(Xb + m*KOUT);
    s.x += a*xv.x; s.y += a*xv.y; s.z += a*xv.z; s.w += a*xv.w;
  }
  *(float4*)(Y + (b*NN + n0 + nr)*KOUT + f4*4) = s;
}

__global__ void finalize(const float* __restrict__ agg2, const float* __restrict__ b2,
                         const float* __restrict__ clw, const float* __restrict__ clb,
                         float* __restrict__ out)
{
  __shared__ float red[256];
  int bb = blockIdx.x, tid = threadIdx.x;
  float acc = 0.f;
  for (int i = tid; i < NN*64; i += 256){
    int j = i & 63;
    float v = agg2[bb*NN*64 + i] + b2[j];
    acc += fmaxf(v, 0.f) * clw[j];
  }
  red[tid] = acc; __syncthreads();
  for (int sfd=128; sfd>0; sfd>>=1){
    if (tid < sfd) red[tid] += red[tid+sfd];
    __syncthreads();
  }
  if (tid==0) out[bb] = red[0]*(1.0f/NN) + clb[0];
}

extern "C" void kernel_launch(void* const* d_in, const int* in_sizes, int n_in,
                              void* d_out, int out_size, void* d_ws, size_t ws_size,
                              hipStream_t stream)
{
  const float* x    = (const float*)d_in[0];
  const int*   ei   = (const int*)  d_in[1];
  const float* wih0 = (const float*)d_in[2];
  const float* whh0 = (const float*)d_in[3];
  const float* bih0 = (const float*)d_in[4];
  const float* bhh0 = (const float*)d_in[5];
  const float* wih1 = (const float*)d_in[6];
  const float* whh1 = (const float*)d_in[7];
  const float* bih1 = (const float*)d_in[8];
  const float* bhh1 = (const float*)d_in[9];
  const float* wih2 = (const float*)d_in[10];
  const float* whh2 = (const float*)d_in[11];
  const float* bih2 = (const float*)d_in[12];
  const float* bhh2 = (const float*)d_in[13];
  const float* g1w  = (const float*)d_in[14];
  const float* g1b  = (const float*)d_in[15];
  const float* g2w  = (const float*)d_in[16];
  const float* g2b  = (const float*)d_in[17];
  const float* clw  = (const float*)d_in[18];
  const float* clb  = (const float*)d_in[19];
  float* out = (float*)d_out;

  char* ws = (char*)d_ws;
  float* feats = (float*)(ws);                 // [4096,128]  2 MB
  float* xl1   = (float*)(ws + 2097152);       // [8,512,128] 2 MB
  float* agg1  = (float*)(ws + 4194304);       // [8,512,128] 2 MB
  float* xl2   = (float*)(ws + 6291456);       // [8,512,64]  1 MB
  float* agg2  = (float*)(ws + 7340032);       // [8,512,64]  1 MB
  float* A     = (float*)(ws + 8388608);       // [512,512]   1 MB
  float* deg   = (float*)(ws + 9437184);       // [512]
  // fp16 weight planes: 40 chunks x 16KB = 640KB.
  // Overlaps xl2 region: wp is consumed by lstm_scan BEFORE xl2 is written
  // (strict stream order), so reuse is safe.
  _Float16* wpW = (_Float16*)(ws + 6291456);

  prep_w<<<(5*G4*HID)/256, 256, 0, stream>>>(whh0, wih1, whh1, wih2, whh2, wpW);

  hipMemsetAsync(A, 0, NN*NN*sizeof(float), stream);
  deg_init <<<2, 256, 0, stream>>>(deg);
  deg_edges<<<EE/256, 256, 0, stream>>>(ei, deg);
  build_A  <<<(EE+NN+255)/256, 256, 0, stream>>>(ei, deg, A);

  lstm_scan<<<256, NTHR, 0, stream>>>(x, wih0, bih0, bhh0,
      bih1, bhh1, bih2, bhh2, wpW, feats);

  gcn_gemm<128><<<(4096*128)/256, 256, 0, stream>>>(feats, g1w, nullptr, xl1);
  gcn_agg<128><<<dim3(NB, NN/16), 512, 0, stream>>>(A, xl1, agg1);
  gcn_gemm<64><<<(4096*64)/256, 256, 0, stream>>>(agg1, g2w, g1b, xl2);
  gcn_agg<64><<<dim3(NB, NN/16), 256, 0, stream>>>(A, xl2, agg2);
  finalize<<<NB, 256, 0, stream>>>(agg2, g2b, clw, clb, out);
}

// Round 6
// 822.731 us; speedup vs baseline: 2.5567x; 2.1206x over previous
//
#include <hip/hip_runtime.h>

#define TT   64
#define NB   8
#define NN   512
#define HID  128
#define G4   512
#define EE   8192
#define SBLK 16
#define NTHR 512

__device__ __forceinline__ float sigf(float x){ return 1.0f/(1.0f+expf(-x)); }

using half8 = __attribute__((ext_vector_type(8))) _Float16;
using f32x4 = __attribute__((ext_vector_type(4))) float;

// async global->LDS, 16B per lane; LDS dest = wave-uniform base + lane*16
__device__ __forceinline__ void gload16(const float* g, float* l){
  __builtin_amdgcn_global_load_lds(
      (const __attribute__((address_space(1))) void*)g,
      (__attribute__((address_space(3))) void*)l, 16, 0, 0);
}

// ---------------------------------------------------------------------------
// Weight prep (unchanged layout from verified R5): f32 [512][128] x5 ->
// fp16 planes in MFMA B-fragment order. Matrix m occupies 65536 fp16 (128KB):
//   [kt(4)][half(2)][nl(16)][lane(64)][8 fp16]
// lane l elem j <-> W[n=(half*16+nl)*16+(l&15)][k=kt*32+8*(l>>4)+j]
// mats: 0=whh0 1=wih1 2=whh1 3=wih2 4=whh2
// ---------------------------------------------------------------------------
__global__ void prep_w(const float* __restrict__ whh0, const float* __restrict__ wih1,
                       const float* __restrict__ whh1, const float* __restrict__ wih2,
                       const float* __restrict__ whh2, _Float16* __restrict__ wp)
{
  int idx = blockIdx.x*256 + threadIdx.x;      // 5*512*128 total
  int mat = idx >> 16;
  int r   = (idx >> 7) & 511;
  int k   = idx & 127;
  const float* src = (mat==0)?whh0:(mat==1)?wih1:(mat==2)?whh1:(mat==3)?wih2:whh2;
  float v = src[r*HID + k];
  int kt = k >> 5, kk = k & 31, s0 = kk >> 3, j = kk & 7;
  int nt = r >> 4, half = nt >> 4, nl = nt & 15;
  int l  = (r & 15) + 16*s0;
  wp[(mat*8 + kt*2 + half)*8192 + nl*512 + l*8 + j] = (_Float16)v;
}

// ---------------------------------------------------------------------------
// One layer-phase of the scan over timesteps [ch*TCH, ch*TCH+TCH).
// whh resident in LDS (WL, 128KB); wih (L>0) resident in 64 VGPRs of B-frags;
// prev-layer h read from hout (fragment-ordered 4KB tiles, coalesced);
// this layer's h written back to the SAME hout tile (read-then-overwrite,
// made safe by the full-drain __syncthreads at the top of each step).
// h of current layer: split fp16 hi/lo in LDS hb (R5-verified swizzle).
// ---------------------------------------------------------------------------
template<int L>
__device__ __forceinline__ void scan_phase(
    int ch, int TCH, const _Float16* __restrict__ wp, _Float16* __restrict__ hout,
    float* WL, _Float16* hb, const float* xall,
    float4 bL, float4 w0g, float (&cs)[4], float (&hlast)[4])
{
  const int tid  = threadIdx.x;
  const int lane = tid & 63, wv = tid >> 6, row = lane & 15;
  const int u    = 16*wv + row;
  const int blk  = blockIdx.x;

  // ---- load whh_L into LDS (overwrite-safe: barrier before, drain after)
  const float* whhG = (const float*)(wp + (L==0?0:(L==1?2:4))*65536);
  __syncthreads();                         // everyone done with previous WL
  #pragma unroll
  for (int i=0;i<16;i++)
    gload16(whhG + i*2048 + tid*4, WL + i*2048 + tid*4);
  __syncthreads();                         // drains vmcnt -> WL ready

  // ---- wih_L B-fragments into registers (L>0)
  half8 wih[4][4];
  if (L>0){
    const char* wihG = (const char*)(wp + (L==1?1:3)*65536);
    #pragma unroll
    for (int g=0;g<4;g++)
      #pragma unroll
      for (int kt=0;kt<4;kt++)
        wih[g][kt] = *(const half8*)(wihG + kt*32768 + (g>>1)*16384
                                     + (wv+8*(g&1))*1024 + lane*16);
  }

  const char* hout_c = (const char*)hout;
  half8 pfA[4];
  if (L>0){
    #pragma unroll
    for (int kt=0;kt<4;kt++)
      pfA[kt] = *(const half8*)(hout_c + (0*256 + blk)*4096 + kt*1024 + lane*16);
  }

  const char* hbL = (const char*)hb + L*8192;
  const char* WLc = (const char*)WL;

  #pragma unroll 1
  for (int tt=0; tt<TCH; ++tt){
    const int t = ch*TCH + tt;
    __syncthreads();                       // h(t-1) hb writes visible; pf drained

    f32x4 acc[4];
    #pragma unroll
    for (int g=0;g<4;g++) acc[g] = (f32x4){bL[g],bL[g],bL[g],bL[g]};

    if (L>0){                              // input-projection term (prev-layer h)
      #pragma unroll
      for (int g=0;g<4;g++)
        #pragma unroll
        for (int kt=0;kt<4;kt++)
          acc[g] = __builtin_amdgcn_mfma_f32_16x16x32_f16(pfA[kt], wih[g][kt], acc[g],0,0,0);
    }

    // recurrent term: A = h(t-1) hi/lo from hb, B = whh from LDS
    half8 ahh[4], ahl[4];
    #pragma unroll
    for (int kt=0;kt<4;kt++){
      int rb = row*256 + (((kt<<6) + ((lane>>4)<<4)) ^ ((row&7)<<4));
      ahh[kt] = *(const half8*)(hbL + rb);
      ahl[kt] = *(const half8*)(hbL + 4096 + rb);
    }
    #pragma unroll
    for (int g=0;g<4;g++)
      #pragma unroll
      for (int kt=0;kt<4;kt++){
        half8 B = *(const half8*)(WLc + kt*32768 + (g>>1)*16384
                                  + (wv+8*(g&1))*1024 + lane*16);
        acc[g] = __builtin_amdgcn_mfma_f32_16x16x32_f16(ahh[kt], B, acc[g],0,0,0);
        acc[g] = __builtin_amdgcn_mfma_f32_16x16x32_f16(ahl[kt], B, acc[g],0,0,0);
      }

    __syncthreads();                       // all hb reads done before overwrite

    if (L>0 && tt+1 < TCH){                // prefetch next prev-layer tile
      #pragma unroll
      for (int kt=0;kt<4;kt++)
        pfA[kt] = *(const half8*)(hout_c + ((tt+1)*256 + blk)*4096 + kt*1024 + lane*16);
    }

    #pragma unroll
    for (int r=0;r<4;r++){
      float iv=acc[0][r], fv=acc[1][r], gv=acc[2][r], ov=acc[3][r];
      if (L==0){
        float xv = xall[t*SBLK + 4*(lane>>4)+r];
        iv+=xv*w0g[0]; fv+=xv*w0g[1]; gv+=xv*w0g[2]; ov+=xv*w0g[3];
      }
      float cn = sigf(fv)*cs[r] + sigf(iv)*tanhf(gv);
      cs[r]=cn; float hn = sigf(ov)*tanhf(cn);
      _Float16 hh = (_Float16)hn;
      _Float16 hl = (_Float16)(hn - (float)hh);
      int sq = 4*(lane>>4)+r;
      int wb = sq*256 + ((u*2) ^ ((sq&7)<<4));
      *(_Float16*)((char*)hbL + wb)        = hh;
      *(_Float16*)((char*)hbL + 4096 + wb) = hl;
      if (L<2){                            // fragment-ordered hout write (hi only)
        _Float16* hp = (_Float16*)(hout_c + (tt*256 + blk)*4096);
        hp[(wv>>1)*512 + (2*(wv&1)+((lane&15)>>3))*128 + sq*8 + (lane&7)] = hh;
      }
      if (L==2 && t==TT-1) hlast[r]=hn;
    }
  }
}

// ---------------------------------------------------------------------------
// Fused 3-layer LSTM scan, layer-sequential with LDS-resident whh.
// 256 blocks x 512 thr; per block 16 seqs through all 3 layers x 64 steps,
// in NCH chunks of TCH timesteps (chunking only bounds hout workspace).
// ---------------------------------------------------------------------------
__global__ __launch_bounds__(NTHR,2) void lstm_scan(
    const float* __restrict__ x,    const float* __restrict__ wih0,
    const float* __restrict__ bih0, const float* __restrict__ bhh0,
    const float* __restrict__ bih1, const float* __restrict__ bhh1,
    const float* __restrict__ bih2, const float* __restrict__ bhh2,
    const _Float16* __restrict__ wp, _Float16* __restrict__ hout,
    float* __restrict__ feats, int TCH, int NCH)
{
  __shared__ __align__(16) float WL[32768];        // 128 KB resident whh
  __shared__ __align__(16) _Float16 hb[3*4096];    // 24 KB: 3 layers x {hi,lo} swizzled
  __shared__ __align__(16) float xall[TT*SBLK];    // 4 KB

  const int tid  = threadIdx.x;
  const int lane = tid & 63, wv = tid >> 6;
  const int u    = 16*wv + (lane & 15);
  const int s0   = blockIdx.x * SBLK;
  const int b    = s0 >> 9, n0 = s0 & (NN-1);

  for (int i = tid; i < 3*4096; i += NTHR) hb[i] = (_Float16)0.0f;
  for (int i = tid; i < TT*SBLK; i += NTHR)
    xall[i] = x[(b*TT + (i>>4))*NN + n0 + (i&15)];

  float4 b0, b1, b2, w0g;
  #pragma unroll
  for (int g=0; g<4; g++){
    b0[g]  = bih0[g*HID+u] + bhh0[g*HID+u];
    b1[g]  = bih1[g*HID+u] + bhh1[g*HID+u];
    b2[g]  = bih2[g*HID+u] + bhh2[g*HID+u];
    w0g[g] = wih0[g*HID+u];
  }

  float cs0[4]={0,0,0,0}, cs1[4]={0,0,0,0}, cs2[4]={0,0,0,0};
  float hlast[4]={0,0,0,0};

  #pragma unroll 1
  for (int ch=0; ch<NCH; ++ch){
    scan_phase<0>(ch, TCH, wp, hout, WL, hb, xall, b0, w0g, cs0, hlast);
    scan_phase<1>(ch, TCH, wp, hout, WL, hb, xall, b1, w0g, cs1, hlast);
    scan_phase<2>(ch, TCH, wp, hout, WL, hb, xall, b2, w0g, cs2, hlast);
  }

  #pragma unroll
  for (int r=0;r<4;r++)
    feats[(s0 + 4*(lane>>4) + r)*HID + u] = hlast[r];
}

// ---------------------------------------------------------------------------
// GCN part (unchanged from verified baseline)
// ---------------------------------------------------------------------------
template<int KOUT>
__global__ void gcn_gemm(const float* __restrict__ in, const float* __restrict__ W,
                         const float* __restrict__ pre_bias, float* __restrict__ out)
{
  int id  = blockIdx.x*256 + threadIdx.x;
  int row = id / KOUT;
  int o   = id & (KOUT-1);
  const float4* a4 = (const float4*)(in + row*HID);
  const float4* w4 = (const float4*)(W + o*HID);
  float acc = 0.f;
  if (pre_bias){
    const float4* b4 = (const float4*)pre_bias;
    #pragma unroll 8
    for (int k=0;k<HID/4;k++){
      float4 av=a4[k], wv=w4[k], bv=b4[k];
      acc += fmaxf(av.x+bv.x,0.f)*wv.x + fmaxf(av.y+bv.y,0.f)*wv.y
           + fmaxf(av.z+bv.z,0.f)*wv.z + fmaxf(av.w+bv.w,0.f)*wv.w;
    }
  } else {
    #pragma unroll 8
    for (int k=0;k<HID/4;k++){
      float4 av=a4[k], wv=w4[k];
      acc += av.x*wv.x + av.y*wv.y + av.z*wv.z + av.w*wv.w;
    }
  }
  out[id] = acc;
}

__global__ void deg_init(float* deg){
  int i = blockIdx.x*256 + threadIdx.x;
  if (i < NN) deg[i] = 1.0f;             // self-loop
}
__global__ void deg_edges(const int* __restrict__ ei, float* deg){
  int e = blockIdx.x*256 + threadIdx.x;
  if (e < EE) atomicAdd(&deg[ei[EE+e]], 1.0f);
}
__global__ void build_A(const int* __restrict__ ei, const float* __restrict__ deg,
                        float* __restrict__ A){
  int e = blockIdx.x*256 + threadIdx.x;
  if (e < EE){
    int s = ei[e], d = ei[EE+e];
    atomicAdd(&A[d*NN+s], rsqrtf(deg[s])*rsqrtf(deg[d]));
  } else if (e < EE+NN){
    int n = e - EE;
    atomicAdd(&A[n*NN+n], 1.0f/deg[n]);
  }
}

template<int KOUT>
__global__ __launch_bounds__(512) void gcn_agg(const float* __restrict__ A,
    const float* __restrict__ X, float* __restrict__ Y)
{
  const int F4 = KOUT/4;
  const int TN = 16;
  __shared__ __align__(16) float As[TN*NN];
  const int b = blockIdx.x, n0 = blockIdx.y*TN;
  const int tid = threadIdx.x;
  const int f4 = tid & (F4-1), nr = tid / F4;
  for (int i = tid; i < TN*NN; i += TN*F4) As[i] = A[n0*NN + i];
  __syncthreads();
  const float* Xb = X + b*NN*KOUT + f4*4;
  const float* Ar = As + nr*NN;
  float4 s = {0,0,0,0};
  #pragma unroll 4
  for (int m=0;m<NN;m++){
    float a = Ar[m];
    float4 xv = *(const float4*)(Xb + m*KOUT);
    s.x += a*xv.x; s.y += a*xv.y; s.z += a*xv.z; s.w += a*xv.w;
  }
  *(float4*)(Y + (b*NN + n0 + nr)*KOUT + f4*4) = s;
}

__global__ void finalize(const float* __restrict__ agg2, const float* __restrict__ b2,
                         const float* __restrict__ clw, const float* __restrict__ clb,
                         float* __restrict__ out)
{
  __shared__ float red[256];
  int bb = blockIdx.x, tid = threadIdx.x;
  float acc = 0.f;
  for (int i = tid; i < NN*64; i += 256){
    int j = i & 63;
    float v = agg2[bb*NN*64 + i] + b2[j];
    acc += fmaxf(v, 0.f) * clw[j];
  }
  red[tid] = acc; __syncthreads();
  for (int sfd=128; sfd>0; sfd>>=1){
    if (tid < sfd) red[tid] += red[tid+sfd];
    __syncthreads();
  }
  if (tid==0) out[bb] = red[0]*(1.0f/NN) + clb[0];
}

extern "C" void kernel_launch(void* const* d_in, const int* in_sizes, int n_in,
                              void* d_out, int out_size, void* d_ws, size_t ws_size,
                              hipStream_t stream)
{
  const float* x    = (const float*)d_in[0];
  const int*   ei   = (const int*)  d_in[1];
  const float* wih0 = (const float*)d_in[2];
  const float* whh0 = (const float*)d_in[3];
  const float* bih0 = (const float*)d_in[4];
  const float* bhh0 = (const float*)d_in[5];
  const float* wih1 = (const float*)d_in[6];
  const float* whh1 = (const float*)d_in[7];
  const float* bih1 = (const float*)d_in[8];
  const float* bhh1 = (const float*)d_in[9];
  const float* wih2 = (const float*)d_in[10];
  const float* whh2 = (const float*)d_in[11];
  const float* bih2 = (const float*)d_in[12];
  const float* bhh2 = (const float*)d_in[13];
  const float* g1w  = (const float*)d_in[14];
  const float* g1b  = (const float*)d_in[15];
  const float* g2w  = (const float*)d_in[16];
  const float* g2b  = (const float*)d_in[17];
  const float* clw  = (const float*)d_in[18];
  const float* clb  = (const float*)d_in[19];
  float* out = (float*)d_out;

  char* ws = (char*)d_ws;
  float* feats = (float*)(ws);                 // [4096,128]  2 MB
  float* xl1   = (float*)(ws + 2097152);       // [8,512,128] 2 MB (post-lstm)
  float* agg1  = (float*)(ws + 4194304);       // [8,512,128] 2 MB (post-lstm)
  float* xl2   = (float*)(ws + 6291456);       // [8,512,64]  1 MB (post-lstm)
  float* agg2  = (float*)(ws + 7340032);       // [8,512,64]  1 MB (post-lstm)
  float* A     = (float*)(ws + 8388608);       // [512,512]   1 MB
  float* deg   = (float*)(ws + 9437184);       // [512]

  // Workspace-adaptive chunking: hout = [TCH][256 blk][4KB tile] fp16.
  // Big ws: place wp+hout past the GCN footprint. Small ws: overlay hout on
  // xl1/agg1 and wp on xl2 (all consumed/written strictly after lstm_scan).
  int TCH; _Float16* wpW; _Float16* houtW;
  if (ws_size >= 77312000ULL){                 // 10.2MB + 64MB
    TCH = 64; wpW = (_Float16*)(ws + 9441280); houtW = (_Float16*)(ws + 10203136);
  } else if (ws_size >= 26980352ULL){          // 10.2MB + 16MB
    TCH = 16; wpW = (_Float16*)(ws + 9441280); houtW = (_Float16*)(ws + 10203136);
  } else {                                     // fits baseline 9.44MB footprint
    TCH = 4;  wpW = (_Float16*)(ws + 6291456); houtW = (_Float16*)(ws + 2097152);
  }
  int NCH = TT / TCH;

  prep_w<<<(5*G4*HID)/256, 256, 0, stream>>>(whh0, wih1, whh1, wih2, whh2, wpW);

  hipMemsetAsync(A, 0, NN*NN*sizeof(float), stream);
  deg_init <<<2, 256, 0, stream>>>(deg);
  deg_edges<<<EE/256, 256, 0, stream>>>(ei, deg);
  build_A  <<<(EE+NN+255)/256, 256, 0, stream>>>(ei, deg, A);

  lstm_scan<<<256, NTHR, 0, stream>>>(x, wih0, bih0, bhh0,
      bih1, bhh1, bih2, bhh2, wpW, houtW, feats, TCH, NCH);

  gcn_gemm<128><<<(4096*128)/256, 256, 0, stream>>>(feats, g1w, nullptr, xl1);
  gcn_agg<128><<<dim3(NB, NN/16), 512, 0, stream>>>(A, xl1, agg1);
  gcn_gemm<64><<<(4096*64)/256, 256, 0, stream>>>(agg1, g2w, g1b, xl2);
  gcn_agg<64><<<dim3(NB, NN/16), 256, 0, stream>>>(A, xl2, agg2);
  finalize<<<NB, 256, 0, stream>>>(agg2, g2b, clw, clb, out);
}